// Round 11
// baseline (4606.943 us; speedup 1.0000x reference)
//
#include <hip/hip_runtime.h>

typedef unsigned short u16;
typedef unsigned int   u32;

#define B_    128
#define N_    8192
#define HD_   256
#define X_    768          // 3*HD
#define T_    10
#define SEGS_ 16
#define SEGROWS_ 512       // N_/SEGS_

// d_ws layout (u32 units): packed-transposed weights (bf16 pairs) + f32 biases
#define OFF_IH 0            // [384][1024] u32  (Wih^T, k-pairs)
#define OFF_HH 393216       // [128][1024] u32  (Whh^T)
#define OFF_Q  524288       // [128][256]  u32  (Wq^T)
#define OFF_BS 557056       // [1024] f32  (bih+bhh)
#define OFF_BQ 558080       // [256]  f32  (bq)
#define WS_U32_NEEDED 558336

// ---- persistent per-call state in device globals ----
__device__ float g_h[B_*HD_];
__device__ float g_c[B_*HD_];
__device__ float g_q[B_*HD_];
__device__ float g_pval[B_*SEGS_*3];
__device__ int   g_pidx[B_*SEGS_*3];
__device__ int   g_isf32;
__device__ u32   g_sink[2048*256];   // µbench sink (never read)

struct P {
  const void *enc, *h0, *c0, *x0, *Wih, *bih, *Whh, *bhh, *Wq, *bq;
  void* out;
};

// clang-native vectors: no constructors -> loadable through AS(1) pointers.
typedef u32   u32x4 __attribute__((ext_vector_type(4)));
typedef float f32x4 __attribute__((ext_vector_type(4)));
// explicit global-address-space pointers: guarantee global_load_* (vmcnt-only),
// never flat_load (flat counts in BOTH vmcnt and lgkmcnt -> drained by shfl waits)
typedef const __attribute__((address_space(1))) u32x4* gu4;
typedef const __attribute__((address_space(1))) f32x4* gf4;
typedef const __attribute__((address_space(1))) u32*   gau;
typedef const __attribute__((address_space(1))) float* gaf;

__device__ __forceinline__ float bf2f(u16 u){ return __uint_as_float(((u32)u)<<16); }
__device__ __forceinline__ float lo2f(u32 w){ return __uint_as_float(w<<16); }
__device__ __forceinline__ float hi2f(u32 w){ return __uint_as_float(w & 0xffff0000u); }
__device__ __forceinline__ u16 f2bf(float f){
  u32 u = __float_as_uint(f);
  u32 r = u + 0x7fffu + ((u>>16)&1u);   // RNE
  return (u16)(r>>16);
}

template<bool F32>
__device__ __forceinline__ float ld1(const void* p, size_t i){
  if constexpr (F32) return ((const float*)p)[i];
  else               return bf2f(((const u16*)p)[i]);
}

template<bool F32>
__device__ __forceinline__ void st1(void* p, size_t i, float v){
  if constexpr (F32) ((float*)p)[i] = v;
  else               ((u16*)p)[i]   = f2bf(v);
}

template<bool F32>
__device__ __forceinline__ void ld8(const void* p, size_t i, float* o){
  if constexpr (F32){
    const float4* q = (const float4*)((const float*)p + i);
    float4 a = q[0], b = q[1];
    o[0]=a.x; o[1]=a.y; o[2]=a.z; o[3]=a.w;
    o[4]=b.x; o[5]=b.y; o[6]=b.z; o[7]=b.w;
  } else {
    uint4 u = *(const uint4*)((const u16*)p + i);
    o[0]=lo2f(u.x); o[1]=hi2f(u.x); o[2]=lo2f(u.y); o[3]=hi2f(u.y);
    o[4]=lo2f(u.z); o[5]=hi2f(u.z); o[6]=lo2f(u.w); o[7]=hi2f(u.w);
  }
}

// top-3 insert, jax.lax.top_k tie-break (equal value -> lower index first)
__device__ __forceinline__ void t3ins(float v,int i,
    float&v0,int&i0,float&v1,int&i1,float&v2,int&i2){
  if (v>v0 || (v==v0 && i<i0)) { v2=v1;i2=i1; v1=v0;i1=i0; v0=v;i0=i; }
  else if (v>v1 || (v==v1 && i<i1)) { v2=v1;i2=i1; v1=v;i1=i; }
  else if (v>v2 || (v==v2 && i<i2)) { v2=v;i2=i; }
}

// ---- dtype probe ----
__global__ void k_probe(const void* enc){
  const int lane = threadIdx.x;           // 64 threads
  const u16 u = ((const u16*)enc)[lane*2];
  const float a = fabsf(bf2f(u));
  const bool inr = (a >= 0.0009765625f) && (a <= 1024.0f);
  unsigned long long m = __ballot(inr ? 1 : 0);
  if (lane==0) g_isf32 = (__popcll(m) < 32) ? 1 : 0;
}

// ---- µbench: pure streaming read of enc (round-9 load pattern, consume-free).
// 4 passes x 512MB; per block: contiguous 256KB segment, 16B/lane coalesced.
__global__ __launch_bounds__(256) void k_stream(P p){
  const int bid = blockIdx.x, tid = threadIdx.x;
  gu4 base = (gu4)((const u16*)p.enc) + (size_t)bid*16384 + tid;
  u32 s0=0,s1=0,s2=0,s3=0;
  #pragma unroll 1
  for (int pass=0; pass<4; ++pass){
    #pragma unroll 8
    for (int i=0;i<64;i++){
      u32x4 u = base[(size_t)i*256];
      s0+=u.x; s1+=u.y; s2+=u.z; s3+=u.w;
    }
  }
  g_sink[bid*256+tid] = s0^s1^s2^s3;
}

// ---- k_prep: one-time weight transpose/pack into d_ws (bf16 mode only) ----
__global__ __launch_bounds__(256) void k_prep(P p, u32* ws){
  if (g_isf32) return;                     // legacy path handles f32
  const int bid = blockIdx.x, tid = threadIdx.x;
  const u16* Wih = (const u16*)p.Wih;
  const u16* Whh = (const u16*)p.Whh;
  const u16* Wq  = (const u16*)p.Wq;
  if (bid < 384){
    const int kk = bid;
    for (int r=tid; r<1024; r+=256)
      ws[OFF_IH + kk*1024 + r] =
        (u32)Wih[(size_t)r*768 + 2*kk] | ((u32)Wih[(size_t)r*768 + 2*kk+1] << 16);
    if (bid == 0){
      const u16* bih = (const u16*)p.bih;
      const u16* bhh = (const u16*)p.bhh;
      const u16* bq  = (const u16*)p.bq;
      float* bs  = (float*)(ws + OFF_BS);
      float* bqf = (float*)(ws + OFF_BQ);
      for (int r=tid; r<1024; r+=256) bs[r] = bf2f(bih[r]) + bf2f(bhh[r]);
      if (tid < 256) bqf[tid] = bf2f(bq[tid]);
    }
  } else if (bid < 512){
    const int kk = bid - 384;
    for (int r=tid; r<1024; r+=256)
      ws[OFF_HH + kk*1024 + r] =
        (u32)Whh[(size_t)r*256 + 2*kk] | ((u32)Whh[(size_t)r*256 + 2*kk+1] << 16);
  } else {
    const int kk = bid - 512;
    if (tid < 256)
      ws[OFF_Q + kk*256 + tid] =
        (u32)Wq[(size_t)tid*256 + 2*kk] | ((u32)Wq[(size_t)tid*256 + 2*kk+1] << 16);
  }
}

// ---- lstm_fast: coalesced transposed-weight GEMV (bf16 mode) ----
__device__ void lstm_fast(const P& p, int t, int b, const u32* wsg,
                          float* xs, float* hs, float* hn)
{
  const int d = threadIdx.x;
  __shared__ int idx3[3];
  gau wih = (gau)(wsg + OFF_IH);
  gau whh = (gau)(wsg + OFF_HH);
  gau wq  = (gau)(wsg + OFF_Q);
  gaf bs  = (gaf)(wsg + OFF_BS);
  gaf bqf = (gaf)(wsg + OFF_BQ);

  float cd;
  if (t == 0){
    for (int i=d;i<X_;i+=256) xs[i] = ld1<false>(p.x0, (size_t)b*X_+i);
    hs[d] = ld1<false>(p.h0, (size_t)b*HD_+d);
    cd    = ld1<false>(p.c0, (size_t)b*HD_+d);
  } else {
    if (d==0){
      float v0=-3.4e38f,v1=-3.4e38f,v2=-3.4e38f; int i0=-1,i1=-1,i2=-1;
      const float* pv = g_pval + b*SEGS_*3;
      const int*   pi = g_pidx + b*SEGS_*3;
      for (int s=0;s<SEGS_*3;s++) t3ins(pv[s],pi[s],v0,i0,v1,i1,v2,i2);
      idx3[0]=i0; idx3[1]=i1; idx3[2]=i2;
      const size_t ib = (size_t)T_*B_*N_ + (size_t)(t-1)*B_*3 + (size_t)b*3;
      st1<false>(p.out, ib+0, (float)i0);
      st1<false>(p.out, ib+1, (float)i1);
      st1<false>(p.out, ib+2, (float)i2);
    }
    __syncthreads();
    #pragma unroll
    for (int j=0;j<3;j++){
      int jj = idx3[j]; jj = jj<0 ? 0 : (jj>N_-1 ? N_-1 : jj);
      xs[j*HD_+d] = ld1<false>(p.enc, ((size_t)b*N_ + jj)*HD_ + d);
    }
    hs[d] = g_h[b*HD_+d];
    cd    = g_c[b*HD_+d];
  }
  __syncthreads();

  float ga[4], gb[4];
  #pragma unroll
  for (int g=0;g<4;g++){ ga[g] = bs[g*256+d]; gb[g] = 0.f; }

  #pragma unroll 8
  for (int kk=0; kk<384; ++kk){
    const float x0 = xs[2*kk], x1 = xs[2*kk+1];
    #pragma unroll
    for (int g=0; g<4; ++g){
      const u32 w = wih[(size_t)kk*1024 + g*256 + d];
      ga[g] = fmaf(lo2f(w), x0, ga[g]);
      gb[g] = fmaf(hi2f(w), x1, gb[g]);
    }
  }
  #pragma unroll 8
  for (int kk=0; kk<128; ++kk){
    const float h0 = hs[2*kk], h1 = hs[2*kk+1];
    #pragma unroll
    for (int g=0; g<4; ++g){
      const u32 w = whh[(size_t)kk*1024 + g*256 + d];
      ga[g] = fmaf(lo2f(w), h0, ga[g]);
      gb[g] = fmaf(hi2f(w), h1, gb[g]);
    }
  }
  const float gi_ = ga[0]+gb[0], gf_ = ga[1]+gb[1];
  const float gg_ = ga[2]+gb[2], go_ = ga[3]+gb[3];
  const float sig_i = 1.f/(1.f+expf(-gi_));
  const float sig_f = 1.f/(1.f+expf(-gf_));
  const float tan_g = tanhf(gg_);
  const float sig_o = 1.f/(1.f+expf(-go_));
  const float cn = sig_f*cd + sig_i*tan_g;
  const float hv = sig_o*tanhf(cn);
  g_c[b*HD_+d]=cn; g_h[b*HD_+d]=hv; hn[d]=hv;
  __syncthreads();

  float qa = bqf[d], qb_ = 0.f;
  #pragma unroll 8
  for (int kk=0; kk<128; ++kk){
    const u32 w = wq[(size_t)kk*256 + d];
    qa  = fmaf(lo2f(w), hn[2*kk],   qa);
    qb_ = fmaf(hi2f(w), hn[2*kk+1], qb_);
  }
  g_q[b*HD_+d] = qa + qb_;
}

// ---- legacy lstm (f32 mode / ws fallback) ----
template<bool F32>
__device__ void lstm_b(const P& p, int t, int b, float* xs, float* hs, float* hn)
{
  const int d = threadIdx.x;
  __shared__ int idx3[3];

  float cd;
  if (t == 0){
    for (int i=d;i<X_;i+=256) xs[i] = ld1<F32>(p.x0, (size_t)b*X_+i);
    hs[d] = ld1<F32>(p.h0, (size_t)b*HD_+d);
    cd    = ld1<F32>(p.c0, (size_t)b*HD_+d);
  } else {
    if (d==0){
      float v0=-3.4e38f,v1=-3.4e38f,v2=-3.4e38f; int i0=-1,i1=-1,i2=-1;
      const float* pv = g_pval + b*SEGS_*3;
      const int*   pi = g_pidx + b*SEGS_*3;
      for (int s=0;s<SEGS_*3;s++) t3ins(pv[s],pi[s],v0,i0,v1,i1,v2,i2);
      idx3[0]=i0; idx3[1]=i1; idx3[2]=i2;
      const size_t ib = (size_t)T_*B_*N_ + (size_t)(t-1)*B_*3 + (size_t)b*3;
      st1<F32>(p.out, ib+0, (float)i0);
      st1<F32>(p.out, ib+1, (float)i1);
      st1<F32>(p.out, ib+2, (float)i2);
    }
    __syncthreads();
    #pragma unroll
    for (int j=0;j<3;j++){
      int jj = idx3[j]; jj = jj<0 ? 0 : (jj>N_-1 ? N_-1 : jj);
      xs[j*HD_+d] = ld1<F32>(p.enc, ((size_t)b*N_ + jj)*HD_ + d);
    }
    hs[d] = g_h[b*HD_+d];
    cd    = g_c[b*HD_+d];
  }
  __syncthreads();

  float g4[4];
  #pragma unroll
  for (int gi=0;gi<4;gi++){
    const int row = gi*HD_ + d;
    float acc = ld1<F32>(p.bih,row) + ld1<F32>(p.bhh,row);
    #pragma unroll 4
    for (int kk=0;kk<X_/8;kk++){
      float w[8]; ld8<F32>(p.Wih, (size_t)row*X_ + kk*8, w);
      #pragma unroll
      for (int j=0;j<8;j++) acc = fmaf(xs[kk*8+j], w[j], acc);
    }
    #pragma unroll 4
    for (int kk=0;kk<HD_/8;kk++){
      float w[8]; ld8<F32>(p.Whh, (size_t)row*HD_ + kk*8, w);
      #pragma unroll
      for (int j=0;j<8;j++) acc = fmaf(hs[kk*8+j], w[j], acc);
    }
    g4[gi]=acc;
  }
  const float sig_i = 1.f/(1.f+expf(-g4[0]));
  const float sig_f = 1.f/(1.f+expf(-g4[1]));
  const float tan_g = tanhf(g4[2]);
  const float sig_o = 1.f/(1.f+expf(-g4[3]));
  const float cn = sig_f*cd + sig_i*tan_g;
  const float hv = sig_o*tanhf(cn);
  g_c[b*HD_+d]=cn; g_h[b*HD_+d]=hv; hn[d]=hv;
  __syncthreads();

  float acc = ld1<F32>(p.bq,d);
  #pragma unroll 4
  for (int kk=0;kk<HD_/8;kk++){
    float w[8]; ld8<F32>(p.Wq, (size_t)d*HD_ + kk*8, w);
    #pragma unroll
    for (int j=0;j<8;j++) acc = fmaf(hn[kk*8+j], w[j], acc);
  }
  g_q[b*HD_+d]=acc;
}

__global__ __launch_bounds__(256) void k_lstm(P p, int t, u32* ws, int ws_ok)
{
  __shared__ float xs[X_], hs[HD_], hn[HD_];
  if (!g_isf32 && ws_ok) lstm_fast(p, t, blockIdx.x, ws, xs, hs, hn);
  else if (g_isf32)      lstm_b<true >(p, t, blockIdx.x, xs, hs, hn);
  else                   lstm_b<false>(p, t, blockIdx.x, xs, hs, hn);
}

// ---- K2: logits — round-10 engine, byte-identical (control) ----
template<bool F32>
__device__ void logits_b(const P& p, int t, int b, int seg,
                         float* qs, float* lbuf, float (*sv)[3], int (*si)[3])
{
  const int tid  = threadIdx.x;
  const int wave = tid>>6;
  const int l    = tid&63;
  const int kl   = l&31;
  const int half = l>>5;

  for (int i=tid;i<HD_;i+=256) qs[i] = g_q[b*HD_+i];
  __syncthreads();

  float v0=-3.4e38f,v1=-3.4e38f,v2=-3.4e38f; int i0=-1,i1=-1,i2=-1;
  const int rowg0 = seg*SEGROWS_;

  if constexpr (!F32){
    float qv[8];
    #pragma unroll
    for (int j=0;j<8;j++) qv[j] = qs[kl*8+j];

    const u16* encb = (const u16*)p.enc + ((size_t)b*N_ + (size_t)seg*SEGROWS_)*HD_;
    const int wr0 = wave*128;
    gu4 gbase = (gu4)(encb + ((size_t)(wr0 + half))*HD_ + kl*8);

    const int ph = ((int)blockIdx.x * 37 + wave * 16) & 63;

    u32x4 pf[8];
    #pragma unroll
    for (int ii=0;ii<8;ii++) pf[ii] = gbase[(size_t)(((ii+ph)&63))*64];

    #pragma unroll 1
    for (int ito=0; ito<8; ++ito){
      #pragma unroll
      for (int ii=0;ii<8;ii++){
        const int s = ito*8 + ii;
        u32x4 u = pf[ii];
        if (ito < 7) pf[ii] = gbase[(size_t)(((s+8+ph)&63))*64];
        float acc =       qv[0]*lo2f(u.x);
        acc = fmaf(qv[1], hi2f(u.x), acc);
        acc = fmaf(qv[2], lo2f(u.y), acc);
        acc = fmaf(qv[3], hi2f(u.y), acc);
        acc = fmaf(qv[4], lo2f(u.z), acc);
        acc = fmaf(qv[5], hi2f(u.z), acc);
        acc = fmaf(qv[6], lo2f(u.w), acc);
        acc = fmaf(qv[7], hi2f(u.w), acc);
        acc += __shfl_xor(acc, 1, 64);
        acc += __shfl_xor(acc, 2, 64);
        acc += __shfl_xor(acc, 4, 64);
        acc += __shfl_xor(acc, 8, 64);
        acc += __shfl_xor(acc, 16, 64);
        const int itp = (s + ph) & 63;
        const int row = wr0 + 2*itp + half;
        if (kl==0) lbuf[row] = acc;
        t3ins(acc, rowg0 + row, v0,i0,v1,i1,v2,i2);
      }
    }
  } else {
    const float* encb = (const float*)p.enc + ((size_t)b*N_ + (size_t)seg*SEGROWS_)*HD_;
    for (int row=tid; row<SEGROWS_; row+=256){
      gf4 rp = (gf4)(encb + (size_t)row*HD_);
      float acc = 0.f;
      #pragma unroll 8
      for (int k=0;k<64;k++){
        f32x4 v = rp[k];
        const float* qk = &qs[k*4];
        acc = fmaf(v.x, qk[0], acc);
        acc = fmaf(v.y, qk[1], acc);
        acc = fmaf(v.z, qk[2], acc);
        acc = fmaf(v.w, qk[3], acc);
      }
      lbuf[row] = acc;
      t3ins(acc, rowg0 + row, v0,i0,v1,i1,v2,i2);
    }
  }

  if constexpr (!F32){
    if (kl!=0){ v0=v1=v2=-3.4e38f; i0=i1=i2=-1; }
    float w0=__shfl_xor(v0,32,64), w1=__shfl_xor(v1,32,64), w2=__shfl_xor(v2,32,64);
    int   j0=__shfl_xor(i0,32,64), j1=__shfl_xor(i1,32,64), j2=__shfl_xor(i2,32,64);
    t3ins(w0,j0, v0,i0,v1,i1,v2,i2);
    t3ins(w1,j1, v0,i0,v1,i1,v2,i2);
    t3ins(w2,j2, v0,i0,v1,i1,v2,i2);
  } else {
    #pragma unroll
    for (int d=1; d<64; d<<=1){
      float w0=__shfl_xor(v0,d,64), w1=__shfl_xor(v1,d,64), w2=__shfl_xor(v2,d,64);
      int   j0=__shfl_xor(i0,d,64), j1=__shfl_xor(i1,d,64), j2=__shfl_xor(i2,d,64);
      t3ins(w0,j0, v0,i0,v1,i1,v2,i2);
      t3ins(w1,j1, v0,i0,v1,i1,v2,i2);
      t3ins(w2,j2, v0,i0,v1,i1,v2,i2);
    }
  }
  if (l==0){
    sv[wave][0]=v0; sv[wave][1]=v1; sv[wave][2]=v2;
    si[wave][0]=i0; si[wave][1]=i1; si[wave][2]=i2;
  }
  __syncthreads();

  if (tid==0){
    float w0=-3.4e38f,w1=-3.4e38f,w2=-3.4e38f; int j0=-1,j1=-1,j2=-1;
    for (int s=0;s<4;s++)
      for (int k=0;k<3;k++)
        t3ins(sv[s][k],si[s][k],w0,j0,w1,j1,w2,j2);
    float* pv = g_pval + (b*SEGS_+seg)*3;
    int*   pi = g_pidx + (b*SEGS_+seg)*3;
    pv[0]=w0; pv[1]=w1; pv[2]=w2;
    pi[0]=j0; pi[1]=j1; pi[2]=j2;
  }

  const size_t obase = (size_t)t*B_*N_ + (size_t)b*N_ + (size_t)seg*SEGROWS_;
  if constexpr (!F32){
    u32* o4 = (u32*)((u16*)p.out + obase);
    o4[tid] = (u32)f2bf(lbuf[2*tid]) | ((u32)f2bf(lbuf[2*tid+1])<<16);
  } else {
    float2* o2 = (float2*)((float*)p.out + obase);
    o2[tid] = make_float2(lbuf[2*tid], lbuf[2*tid+1]);
  }
}

__global__ __launch_bounds__(256) void k_logits(P p, int t)
{
  __shared__ float qs[HD_];
  __shared__ float lbuf[SEGROWS_];
  __shared__ float sv[4][3];
  __shared__ int   si[4][3];
  const int b   = blockIdx.x >> 4;
  const int seg = blockIdx.x & 15;
  if (g_isf32) logits_b<true >(p, t, b, seg, qs, lbuf, sv, si);
  else         logits_b<false>(p, t, b, seg, qs, lbuf, sv, si);
}

// ---- K3: final merge for the last step's indices ----
template<bool F32>
__device__ void final_b(const P& p, int b)
{
  if (threadIdx.x==0){
    float v0=-3.4e38f,v1=-3.4e38f,v2=-3.4e38f; int i0=-1,i1=-1,i2=-1;
    const float* pv = g_pval + b*SEGS_*3;
    const int*   pi = g_pidx + b*SEGS_*3;
    for (int s=0;s<SEGS_*3;s++) t3ins(pv[s],pi[s],v0,i0,v1,i1,v2,i2);
    const size_t ib = (size_t)T_*B_*N_ + (size_t)(T_-1)*B_*3 + (size_t)b*3;
    st1<F32>(p.out, ib+0, (float)i0);
    st1<F32>(p.out, ib+1, (float)i1);
    st1<F32>(p.out, ib+2, (float)i2);
  }
}

__global__ void k_final(P p)
{
  if (g_isf32) final_b<true >(p, blockIdx.x);
  else         final_b<false>(p, blockIdx.x);
}

extern "C" void kernel_launch(void* const* d_in, const int* in_sizes, int n_in,
                              void* d_out, int out_size, void* d_ws, size_t ws_size,
                              hipStream_t stream)
{
  (void)in_sizes; (void)n_in; (void)out_size;
  P p;
  p.enc = d_in[0];
  p.h0  = d_in[1];
  p.c0  = d_in[2];
  // d_in[3] end_node_embed: unused in prediction mode
  p.x0  = d_in[4];
  p.Wih = d_in[5];
  p.bih = d_in[6];
  p.Whh = d_in[7];
  p.bhh = d_in[8];
  p.Wq  = d_in[9];
  p.bq  = d_in[10];
  // d_in[11] max_steps == 10 (fixed by setup_inputs)
  p.out = d_out;

  u32* ws = (u32*)d_ws;
  const int ws_ok = (d_ws != nullptr && ws_size >= (size_t)WS_U32_NEEDED*4) ? 1 : 0;

  k_probe<<<dim3(1),dim3(64),0,stream>>>(p.enc);
  k_stream<<<dim3(2048),dim3(256),0,stream>>>(p);          // pure-read µbench
  if (ws_ok) k_prep<<<dim3(640),dim3(256),0,stream>>>(p, ws);

  for (int t=0;t<T_;t++){
    k_lstm  <<<dim3(B_),        dim3(256),0,stream>>>(p, t, ws, ws_ok);
    k_logits<<<dim3(B_*SEGS_),  dim3(256),0,stream>>>(p, t);
  }
  k_final<<<dim3(B_),dim3(64),0,stream>>>(p);
}